// Round 1
// baseline (380.016 us; speedup 1.0000x reference)
//
#include <hip/hip_runtime.h>
#include <hip/hip_bf16.h>
#include <math.h>

#define NN 20000
#define NE 640000
#define D  128
#define KTOT 512   // concat [aggX | X | aggH | H]
#define NOUT 512   // 4 gates x 128

typedef __attribute__((ext_vector_type(8))) short short8;
typedef __attribute__((ext_vector_type(4))) float floatx4;

static __device__ __forceinline__ unsigned short f2bf(float f) {
    union { float f; unsigned int u; } v; v.f = f;
    unsigned int u = v.u;
    u += 0x7fff + ((u >> 16) & 1);   // round-to-nearest-even
    return (unsigned short)(u >> 16);
}

__global__ void count_kernel(const int* __restrict__ dst, int* __restrict__ cnt) {
    int e = blockIdx.x * blockDim.x + threadIdx.x;
    if (e < NE) atomicAdd(&cnt[dst[e]], 1);
}

__global__ void scan_kernel(const int* __restrict__ cnt, int* __restrict__ row_start,
                            int* __restrict__ cursor) {
    __shared__ int part[1024];
    int t = threadIdx.x;
    const int PER = (NN + 1023) / 1024;  // 20
    int base = t * PER;
    int local = 0;
    for (int i = 0; i < PER; ++i) {
        int idx = base + i;
        if (idx < NN) local += cnt[idx];
    }
    part[t] = local;
    __syncthreads();
    for (int off = 1; off < 1024; off <<= 1) {
        int v = (t >= off) ? part[t - off] : 0;
        __syncthreads();
        part[t] += v;
        __syncthreads();
    }
    int run = part[t] - local;  // exclusive prefix
    for (int i = 0; i < PER; ++i) {
        int idx = base + i;
        if (idx < NN) {
            row_start[idx] = run;
            cursor[idx] = run;
            run += cnt[idx];
        }
    }
    if (t == 1023) row_start[NN] = part[1023];
}

__global__ void fill_kernel(const int* __restrict__ src, const int* __restrict__ dst,
                            const float* __restrict__ ew, int* __restrict__ cursor,
                            int* __restrict__ s_src, float* __restrict__ s_w) {
    int e = blockIdx.x * blockDim.x + threadIdx.x;
    if (e < NE) {
        int d = dst[e];
        int p = atomicAdd(&cursor[d], 1);
        s_src[p] = src[e];
        s_w[p] = ew[e];
    }
}

// One block (128 threads) per node: accumulate weighted mean of X and H rows,
// emit bf16 concat row U[n] = [aggX | X | aggH | H].
__global__ void aggregate_kernel(const float* __restrict__ X, const float* __restrict__ H,
                                 const int* __restrict__ row_start,
                                 const int* __restrict__ s_src, const float* __restrict__ s_w,
                                 unsigned short* __restrict__ U) {
    int n = blockIdx.x;
    int d = threadIdx.x;
    int s0 = row_start[n], s1 = row_start[n + 1];
    float ax = 0.f, ah = 0.f;
    for (int i = s0; i < s1; ++i) {
        int s = s_src[i];
        float w = s_w[i];
        ax += X[s * D + d] * w;
        ah += H[s * D + d] * w;
    }
    float inv = (s1 > s0) ? 1.0f / (float)(s1 - s0) : 1.0f;
    unsigned short* row = U + (size_t)n * KTOT;
    row[d]         = f2bf(ax * inv);
    row[D + d]     = f2bf(X[n * D + d]);
    row[2 * D + d] = f2bf(ah * inv);
    row[3 * D + d] = f2bf(H[n * D + d]);
}

// Build transposed bf16 weight matrix Wt[out_col][k] (k: 0-127 Wx_l, 128-255 Wx_r,
// 256-383 Wh_l, 384-511 Wh_r) and fused bias (bx+bh+bg).
__global__ void weights_kernel(const float* __restrict__ Wx_l, const float* __restrict__ Wx_r,
                               const float* __restrict__ Wh_l, const float* __restrict__ Wh_r,
                               const float* __restrict__ bx, const float* __restrict__ bh,
                               const float* __restrict__ bg,
                               unsigned short* __restrict__ Wt, float* __restrict__ bias) {
    int tid = blockIdx.x * blockDim.x + threadIdx.x;  // 0 .. 512*512-1
    int j = tid >> 9;   // output col (gate-major)
    int k = tid & 511;  // input k
    int g = j >> 7;
    int o = j & 127;
    float w;
    if (k < 128)      w = Wx_l[g * 16384 + k * 128 + o];
    else if (k < 256) w = Wx_r[g * 16384 + (k - 128) * 128 + o];
    else if (k < 384) w = Wh_l[g * 16384 + (k - 256) * 128 + o];
    else              w = Wh_r[g * 16384 + (k - 384) * 128 + o];
    Wt[j * 512 + k] = f2bf(w);
    if (k == 0) bias[j] = bx[g * 128 + o] + bh[g * 128 + o] + bg[g * 128 + o];
}

// Fused GEMM (U[20000,512]bf16 @ Wt^T -> preact[16 nodes x 512]) + peephole-LSTM
// epilogue. Block = 256 threads = 4 waves; wave w owns gate w's 128 columns.
__global__ void __launch_bounds__(256)
gemm_lstm_kernel(const unsigned short* __restrict__ U,
                 const unsigned short* __restrict__ Wt,
                 const float* __restrict__ bias,
                 const float* __restrict__ wc,
                 const float* __restrict__ C,
                 float* __restrict__ out) {
    __shared__ __align__(16) short As[16 * 136];  // 16 rows x 128 k, +8 pad (2-way bank alias = free)
    __shared__ float P[4][16][132];               // gate preact planes

    int m0 = blockIdx.x * 16;
    int tid = threadIdx.x;
    int w = tid >> 6;
    int lane = tid & 63;
    int lm = lane & 15;  // A row / B col
    int lq = lane >> 4;  // k quad

    floatx4 acc[8];
#pragma unroll
    for (int t = 0; t < 8; ++t) acc[t] = (floatx4)(0.f);

    int stage_row = tid >> 4;
    int stage_k = (tid & 15) * 8;
    const unsigned short* urow = U + (size_t)(m0 + stage_row) * 512 + stage_k;

    for (int kb = 0; kb < 512; kb += 128) {
        __syncthreads();
        short8 v = *reinterpret_cast<const short8*>(urow + kb);
        *reinterpret_cast<short8*>(&As[stage_row * 136 + stage_k]) = v;
        __syncthreads();
#pragma unroll
        for (int kk = 0; kk < 128; kk += 32) {
            short8 aF = *reinterpret_cast<const short8*>(&As[lm * 136 + kk + lq * 8]);
            const unsigned short* bbase = Wt + (size_t)(w * 128 + lm) * 512 + kb + kk + lq * 8;
#pragma unroll
            for (int t = 0; t < 8; ++t) {
                short8 bF = *reinterpret_cast<const short8*>(bbase + (size_t)t * 16 * 512);
                acc[t] = __builtin_amdgcn_mfma_f32_16x16x32_bf16(aF, bF, acc[t], 0, 0, 0);
            }
        }
    }

    // C/D layout: col = lane&15, row = (lane>>4)*4 + reg
#pragma unroll
    for (int t = 0; t < 8; ++t)
#pragma unroll
        for (int r = 0; r < 4; ++r)
            P[w][lq * 4 + r][t * 16 + lm] = acc[t][r];
    __syncthreads();

    for (int e = tid; e < 16 * 128; e += 256) {
        int r = e >> 7;
        int o = e & 127;
        int n = m0 + r;
        float c = C[n * D + o];
        float gi = P[0][r][o] + bias[o]       + wc[o] * c;
        float gf = P[1][r][o] + bias[128 + o] + wc[128 + o] * c;
        float gt = P[2][r][o] + bias[256 + o];
        float go = P[3][r][o] + bias[384 + o];
        float I = 1.f / (1.f + expf(-gi));
        float F = 1.f / (1.f + expf(-gf));
        float T = tanhf(gt);
        float cn = F * c + I * T;
        float O = 1.f / (1.f + expf(-(go + wc[256 + o] * cn)));
        float hn = O * tanhf(cn);
        out[(size_t)n * D + o] = hn;
        out[(size_t)NN * D + (size_t)n * D + o] = cn;
    }
}

extern "C" void kernel_launch(void* const* d_in, const int* in_sizes, int n_in,
                              void* d_out, int out_size, void* d_ws, size_t ws_size,
                              hipStream_t stream) {
    const float* X  = (const float*)d_in[0];
    const int* ei   = (const int*)d_in[1];
    const float* ew = (const float*)d_in[2];
    const float* H  = (const float*)d_in[3];
    const float* C  = (const float*)d_in[4];
    const float* Wx_l = (const float*)d_in[5];
    const float* Wx_r = (const float*)d_in[6];
    const float* bx   = (const float*)d_in[7];
    const float* Wh_l = (const float*)d_in[8];
    const float* Wh_r = (const float*)d_in[9];
    const float* bh   = (const float*)d_in[10];
    const float* wc   = (const float*)d_in[11];
    const float* bg   = (const float*)d_in[12];
    float* out = (float*)d_out;

    const int* src = ei;
    const int* dst = ei + NE;

    // workspace layout (all 256B aligned), total ~26.4 MB
    char* ws = (char*)d_ws;
    int*   counts    = (int*)(ws + 0);                 // 80000 B
    int*   row_start = (int*)(ws + 80128);             // 80004 B
    int*   cursor    = (int*)(ws + 160256);            // 80000 B
    int*   s_src     = (int*)(ws + 240384);            // 2560000 B
    float* s_w       = (float*)(ws + 2800384);         // 2560000 B
    unsigned short* U  = (unsigned short*)(ws + 5360384);   // 20480000 B
    unsigned short* Wt = (unsigned short*)(ws + 25840384);  // 524288 B
    float* bias      = (float*)(ws + 26364672);        // 2048 B

    hipMemsetAsync(counts, 0, NN * sizeof(int), stream);
    count_kernel<<<(NE + 255) / 256, 256, 0, stream>>>(dst, counts);
    scan_kernel<<<1, 1024, 0, stream>>>(counts, row_start, cursor);
    fill_kernel<<<(NE + 255) / 256, 256, 0, stream>>>(src, dst, ew, cursor, s_src, s_w);
    weights_kernel<<<(512 * 512) / 256, 256, 0, stream>>>(Wx_l, Wx_r, Wh_l, Wh_r, bx, bh, bg, Wt, bias);
    aggregate_kernel<<<NN, D, 0, stream>>>(X, H, row_start, s_src, s_w, U);
    gemm_lstm_kernel<<<NN / 16, 256, 0, stream>>>(U, Wt, bias, wc, C, out);
}

// Round 2
// 299.921 us; speedup vs baseline: 1.2671x; 1.2671x over previous
//
#include <hip/hip_runtime.h>
#include <math.h>

#define NN 20000
#define NE 640000
#define D  128
#define NPAD 20032   // NN padded by 32 rows for the last GEMM block's A-frag loads

typedef __attribute__((ext_vector_type(8))) short short8;
typedef __attribute__((ext_vector_type(4))) float floatx4;

static __device__ __forceinline__ unsigned short f2bf(float f) {
    union { float f; unsigned int u; } v; v.f = f;
    unsigned int u = v.u;
    u += 0x7fff + ((u >> 16) & 1);   // round-to-nearest-even
    return (unsigned short)(u >> 16);
}
static __device__ __forceinline__ unsigned int pack2bf(float a, float b) {
    return (unsigned int)f2bf(a) | ((unsigned int)f2bf(b) << 16);
}
static __device__ __forceinline__ float bf_lo(unsigned int u) {
    union { unsigned int i; float f; } v; v.i = u << 16; return v.f;
}
static __device__ __forceinline__ float bf_hi(unsigned int u) {
    union { unsigned int i; float f; } v; v.i = u & 0xffff0000u; return v.f;
}
static __device__ __forceinline__ float sigm(float x) { return 1.f / (1.f + __expf(-x)); }
static __device__ __forceinline__ float tanhx(float x) { return 1.f - 2.f / (__expf(2.f * x) + 1.f); }

static __device__ __forceinline__ void load_lds16(const void* g, void* l) {
    __builtin_amdgcn_global_load_lds(
        (const __attribute__((address_space(1))) unsigned int*)g,
        (__attribute__((address_space(3))) unsigned int*)l, 16, 0, 0);
}

__global__ void count_kernel(const int* __restrict__ dst, int* __restrict__ cnt) {
    int e = blockIdx.x * blockDim.x + threadIdx.x;
    if (e < NE) atomicAdd(&cnt[dst[e]], 1);
}

// exclusive prefix of counts -> cursor
__global__ void scan_kernel(const int* __restrict__ cnt, int* __restrict__ cursor) {
    __shared__ int part[1024];
    int t = threadIdx.x;
    const int PER = 20;
    int base = t * PER;
    int c[PER];
    int local = 0;
#pragma unroll
    for (int i = 0; i < PER; ++i) {
        int idx = base + i;
        c[i] = (idx < NN) ? cnt[idx] : 0;
        local += c[i];
    }
    part[t] = local;
    __syncthreads();
    for (int off = 1; off < 1024; off <<= 1) {
        int v = (t >= off) ? part[t - off] : 0;
        __syncthreads();
        part[t] += v;
        __syncthreads();
    }
    int run = part[t] - local;  // exclusive prefix
#pragma unroll
    for (int i = 0; i < PER; ++i) {
        int idx = base + i;
        if (idx < NN) { cursor[idx] = run; run += c[i]; }
    }
}

__global__ void fill_kernel(const int* __restrict__ src, const int* __restrict__ dst,
                            const float* __restrict__ ew, int* __restrict__ cursor,
                            int2* __restrict__ s_e) {
    int e = blockIdx.x * blockDim.x + threadIdx.x;
    if (e < NE) {
        int d = dst[e];
        int p = atomicAdd(&cursor[d], 1);
        s_e[p] = make_int2(src[e], __float_as_int(ew[e]));
    }
}

// fp32 X,H -> bf16 interleaved rows XH[n] = [X dims 0..127 | H dims 0..127]
__global__ void xh_prep_kernel(const float2* __restrict__ X2, const float2* __restrict__ H2,
                               unsigned int* __restrict__ XH32) {
    int t = blockIdx.x * 256 + threadIdx.x;  // 0 .. NN*64-1
    int n = t >> 6, dd = t & 63;
    float2 x = X2[t];
    float2 hh = H2[t];
    XH32[n * 128 + dd]      = pack2bf(x.x, x.y);
    XH32[n * 128 + 64 + dd] = pack2bf(hh.x, hh.y);
}

// one 128-thread block per node; thread d<64 -> aggX dims 2d,2d+1; d>=64 -> aggH
__global__ void aggregate_kernel(const unsigned int* __restrict__ XH32,
                                 const int* __restrict__ cursor,
                                 const int2* __restrict__ s_e,
                                 unsigned int* __restrict__ AGG32) {
    int n = blockIdx.x;
    int d = threadIdx.x;
    int s1 = cursor[n];
    int s0 = (n > 0) ? cursor[n - 1] : 0;
    float a0 = 0.f, a1 = 0.f;
    for (int i = s0; i < s1; ++i) {
        int2 e = s_e[i];
        float w = __int_as_float(e.y);
        unsigned int u = XH32[(size_t)e.x * 128 + d];
        a0 += bf_lo(u) * w;
        a1 += bf_hi(u) * w;
    }
    float inv = (s1 > s0) ? 1.0f / (float)(s1 - s0) : 1.0f;
    AGG32[(size_t)n * 128 + d] = pack2bf(a0 * inv, a1 * inv);
}

// Wt[col][k] bf16, col = gate*128 + o; k: 0-127 Wx_l, 128-255 Wx_r, 256-383 Wh_l, 384-511 Wh_r
__global__ void weights_kernel(const float* __restrict__ Wx_l, const float* __restrict__ Wx_r,
                               const float* __restrict__ Wh_l, const float* __restrict__ Wh_r,
                               const float* __restrict__ bx, const float* __restrict__ bh,
                               const float* __restrict__ bg,
                               unsigned short* __restrict__ Wt, float* __restrict__ bias) {
    int tid = blockIdx.x * blockDim.x + threadIdx.x;  // 0 .. 512*512-1
    int j = tid >> 9;   // output col (gate-major)
    int k = tid & 511;
    int g = j >> 7;
    int o = j & 127;
    float w;
    if (k < 128)      w = Wx_l[g * 16384 + k * 128 + o];
    else if (k < 256) w = Wx_r[g * 16384 + (k - 128) * 128 + o];
    else if (k < 384) w = Wh_l[g * 16384 + (k - 256) * 128 + o];
    else              w = Wh_r[g * 16384 + (k - 384) * 128 + o];
    Wt[j * 512 + k] = f2bf(w);
    if (k == 0) bias[j] = bx[g * 128 + o] + bh[g * 128 + o] + bg[g * 128 + o];
}

// Fused GEMM + peephole-LSTM.
// Block: 64 rows x 512 cols, 256 threads = 4 waves.
// Wave wv: rows m0 + (wv>>1)*32 .. +32, cols: for each gate g, in-gate cols (wv&1)*64 .. +64.
// acc[mt][g][nt] : 2 M-tiles x 4 gates x 4 N-tiles of 16x16 (128 VGPRs).
// All four gates of an output element live in the same lane -> in-register LSTM epilogue.
__global__ void __launch_bounds__(256, 2)
gemm_lstm_kernel(const unsigned short* __restrict__ XH,
                 const unsigned short* __restrict__ AGG,
                 const unsigned short* __restrict__ Wt,
                 const float* __restrict__ bias,
                 const float* __restrict__ wc,
                 const float* __restrict__ C,
                 float* __restrict__ out) {
    __shared__ __align__(16) short Bs[2][16384];  // [buf][col*32 + k], 32 KB each

    int tid = threadIdx.x;
    int wv = tid >> 6, lane = tid & 63;
    int lm = lane & 15, lq = lane >> 4;
    int m0 = blockIdx.x * 64;
    int rg = wv >> 1;   // row group (0/1)
    int h  = wv & 1;    // in-gate column half (0/1)

    floatx4 acc[2][4][4] = {};

    // staging roles: thread t stages col j*64 + (t>>2), 16B piece (t&3)
    const unsigned short* wbase = Wt + (size_t)(tid >> 2) * 512 + (tid & 3) * 8;

    // stage kb=0 into buffer 0
#pragma unroll
    for (int j = 0; j < 8; ++j)
        load_lds16(wbase + (size_t)j * 64 * 512, &Bs[0][j * 2048 + wv * 512]);

    int arow0 = m0 + rg * 32 + lm;        // mt=0 row; mt=1 adds 16
    int afk = lq * 8;

    for (int it = 0; it < 16; ++it) {
        int kb = it * 32;
        __syncthreads();   // drains prior staging (vmcnt0) + guards buffer reuse
        if (it < 15) {
            int kn = kb + 32;
            int buf = (it + 1) & 1;
#pragma unroll
            for (int j = 0; j < 8; ++j)
                load_lds16(wbase + (size_t)j * 64 * 512 + kn, &Bs[buf][j * 2048 + wv * 512]);
        }
        // A frags: U = [aggX | X | aggH | H] segmented over AGG / XH rows of 256 shorts
        const unsigned short* abase = (kb & 128) ? XH : AGG;
        int aoff = (kb & 127) | ((kb & 256) >> 1);
        short8 a0 = *(const short8*)(abase + (size_t)arow0 * 256 + aoff + afk);
        short8 a1 = *(const short8*)(abase + (size_t)(arow0 + 16) * 256 + aoff + afk);

        const short* bsc = Bs[it & 1];
#pragma unroll
        for (int g = 0; g < 4; ++g) {
#pragma unroll
            for (int nt = 0; nt < 4; ++nt) {
                int col = (g << 7) + (h << 6) + (nt << 4) + lm;
                short8 b = *(const short8*)&bsc[(col << 5) + (lq << 3)];
                acc[0][g][nt] = __builtin_amdgcn_mfma_f32_16x16x32_bf16(a0, b, acc[0][g][nt], 0, 0, 0);
                acc[1][g][nt] = __builtin_amdgcn_mfma_f32_16x16x32_bf16(a1, b, acc[1][g][nt], 0, 0, 0);
            }
        }
    }

    // per-lane bias / peephole weights for the 4 in-gate columns this lane owns
    float b_i[4], b_f[4], b_c[4], b_o[4], w0[4], w1[4], w2[4];
#pragma unroll
    for (int nt = 0; nt < 4; ++nt) {
        int cg = (h << 6) + (nt << 4) + lm;
        b_i[nt] = bias[cg];
        b_f[nt] = bias[128 + cg];
        b_c[nt] = bias[256 + cg];
        b_o[nt] = bias[384 + cg];
        w0[nt] = wc[cg];
        w1[nt] = wc[128 + cg];
        w2[nt] = wc[256 + cg];
    }

#pragma unroll
    for (int mt = 0; mt < 2; ++mt) {
#pragma unroll
        for (int r = 0; r < 4; ++r) {
            int row = m0 + rg * 32 + mt * 16 + lq * 4 + r;
            if (row < NN) {
#pragma unroll
                for (int nt = 0; nt < 4; ++nt) {
                    int cg = (h << 6) + (nt << 4) + lm;
                    float c = C[(size_t)row * D + cg];
                    float pi = acc[mt][0][nt][r] + b_i[nt] + w0[nt] * c;
                    float pf = acc[mt][1][nt][r] + b_f[nt] + w1[nt] * c;
                    float pt = acc[mt][2][nt][r] + b_c[nt];
                    float po = acc[mt][3][nt][r] + b_o[nt];
                    float I = sigm(pi);
                    float F = sigm(pf);
                    float T = tanhx(pt);
                    float cn = F * c + I * T;
                    float O = sigm(po + w2[nt] * cn);
                    out[(size_t)row * D + cg] = O * tanhx(cn);
                    out[(size_t)NN * D + (size_t)row * D + cg] = cn;
                }
            }
        }
    }
}

extern "C" void kernel_launch(void* const* d_in, const int* in_sizes, int n_in,
                              void* d_out, int out_size, void* d_ws, size_t ws_size,
                              hipStream_t stream) {
    const float* X  = (const float*)d_in[0];
    const int* ei   = (const int*)d_in[1];
    const float* ew = (const float*)d_in[2];
    const float* H  = (const float*)d_in[3];
    const float* C  = (const float*)d_in[4];
    const float* Wx_l = (const float*)d_in[5];
    const float* Wx_r = (const float*)d_in[6];
    const float* bx   = (const float*)d_in[7];
    const float* Wh_l = (const float*)d_in[8];
    const float* Wh_r = (const float*)d_in[9];
    const float* bh   = (const float*)d_in[10];
    const float* wc   = (const float*)d_in[11];
    const float* bg   = (const float*)d_in[12];
    float* out = (float*)d_out;

    const int* src = ei;
    const int* dst = ei + NE;

    // workspace layout (16B aligned), total ~26.32 MB
    char* ws = (char*)d_ws;
    int*  counts = (int*)(ws + 0);                        //    80,000 B
    int*  cursor = (int*)(ws + 80128);                    //    80,000 B
    int2* s_e    = (int2*)(ws + 160256);                  // 5,120,000 B
    unsigned short* XH  = (unsigned short*)(ws + 5280256);   // NPAD*256*2 = 10,256,384 B
    unsigned short* AGG = (unsigned short*)(ws + 15536640);  // 10,256,384 B
    unsigned short* Wt  = (unsigned short*)(ws + 25793024);  //   524,288 B
    float* bias = (float*)(ws + 26317312);                //     2,048 B

    hipMemsetAsync(counts, 0, NN * sizeof(int), stream);
    count_kernel<<<(NE + 255) / 256, 256, 0, stream>>>(dst, counts);
    scan_kernel<<<1, 1024, 0, stream>>>(counts, cursor);
    fill_kernel<<<(NE + 255) / 256, 256, 0, stream>>>(src, dst, ew, cursor, s_e);
    xh_prep_kernel<<<(NN * 64) / 256, 256, 0, stream>>>((const float2*)X, (const float2*)H,
                                                        (unsigned int*)XH);
    weights_kernel<<<(512 * 512) / 256, 256, 0, stream>>>(Wx_l, Wx_r, Wh_l, Wh_r, bx, bh, bg, Wt, bias);
    aggregate_kernel<<<NN, D, 0, stream>>>((const unsigned int*)XH, cursor, s_e,
                                           (unsigned int*)AGG);
    gemm_lstm_kernel<<<(NN + 63) / 64, 256, 0, stream>>>(XH, AGG, Wt, bias, wc, C, out);
}

// Round 3
// 258.014 us; speedup vs baseline: 1.4728x; 1.1624x over previous
//
#include <hip/hip_runtime.h>
#include <math.h>

#define NN 20000
#define NE 640000
#define D  128
#define NPAD 20032   // NN padded by 32 rows for the last GEMM block's A-frag loads

typedef __attribute__((ext_vector_type(8))) short short8;
typedef __attribute__((ext_vector_type(4))) float floatx4;

static __device__ __forceinline__ unsigned short f2bf(float f) {
    union { float f; unsigned int u; } v; v.f = f;
    unsigned int u = v.u;
    u += 0x7fff + ((u >> 16) & 1);   // round-to-nearest-even
    return (unsigned short)(u >> 16);
}
static __device__ __forceinline__ unsigned int pack2bf(float a, float b) {
    return (unsigned int)f2bf(a) | ((unsigned int)f2bf(b) << 16);
}
static __device__ __forceinline__ float bf_lo(unsigned int u) {
    union { unsigned int i; float f; } v; v.i = u << 16; return v.f;
}
static __device__ __forceinline__ float bf_hi(unsigned int u) {
    union { unsigned int i; float f; } v; v.i = u & 0xffff0000u; return v.f;
}
static __device__ __forceinline__ float sigm(float x) { return 1.f / (1.f + __expf(-x)); }
static __device__ __forceinline__ float tanhx(float x) { return 1.f - 2.f / (__expf(2.f * x) + 1.f); }

static __device__ __forceinline__ void load_lds16(const void* g, void* l) {
    __builtin_amdgcn_global_load_lds(
        (const __attribute__((address_space(1))) unsigned int*)g,
        (__attribute__((address_space(3))) unsigned int*)l, 16, 0, 0);
}

// Fused independent prep: degree count (atomics), X/H -> bf16 pack, weight
// transpose + bias fuse. NE == NN*32 == 640000 threads exactly.
__global__ void __launch_bounds__(256)
prep_kernel(const int* __restrict__ dst, int* __restrict__ cnt,
            const float4* __restrict__ X4, const float4* __restrict__ H4,
            unsigned int* __restrict__ XH32,
            const float* __restrict__ Wx_l, const float* __restrict__ Wx_r,
            const float* __restrict__ Wh_l, const float* __restrict__ Wh_r,
            const float* __restrict__ bx, const float* __restrict__ bh,
            const float* __restrict__ bg,
            unsigned short* __restrict__ Wt, float* __restrict__ bias) {
    int t = blockIdx.x * 256 + threadIdx.x;  // 0 .. 639999
    // 1) degree histogram
    atomicAdd(&cnt[dst[t]], 1);
    // 2) bf16 pack: XH[n] = [X row (128) | H row (128)]
    float4 x = X4[t];
    float4 h = H4[t];
    int n = t >> 5, q = t & 31;
    unsigned int* row = XH32 + n * 128;
    row[2 * q]          = pack2bf(x.x, x.y);
    row[2 * q + 1]      = pack2bf(x.z, x.w);
    row[64 + 2 * q]     = pack2bf(h.x, h.y);
    row[64 + 2 * q + 1] = pack2bf(h.z, h.w);
    // 3) weight transpose: Wt[col][k], col = gate*128+o
    if (t < 512 * 512) {
        int j = t >> 9;
        int k = t & 511;
        int g = j >> 7;
        int o = j & 127;
        float w;
        if (k < 128)      w = Wx_l[g * 16384 + k * 128 + o];
        else if (k < 256) w = Wx_r[g * 16384 + (k - 128) * 128 + o];
        else if (k < 384) w = Wh_l[g * 16384 + (k - 256) * 128 + o];
        else              w = Wh_r[g * 16384 + (k - 384) * 128 + o];
        Wt[j * 512 + k] = f2bf(w);
        if (k == 0) bias[j] = bx[g * 128 + o] + bh[g * 128 + o] + bg[g * 128 + o];
    }
}

// exclusive prefix of counts -> cursor
__global__ void scan_kernel(const int* __restrict__ cnt, int* __restrict__ cursor) {
    __shared__ int part[1024];
    int t = threadIdx.x;
    const int PER = 20;
    int base = t * PER;
    int c[PER];
    int local = 0;
#pragma unroll
    for (int i = 0; i < PER; ++i) {
        int idx = base + i;
        c[i] = (idx < NN) ? cnt[idx] : 0;
        local += c[i];
    }
    part[t] = local;
    __syncthreads();
    for (int off = 1; off < 1024; off <<= 1) {
        int v = (t >= off) ? part[t - off] : 0;
        __syncthreads();
        part[t] += v;
        __syncthreads();
    }
    int run = part[t] - local;  // exclusive prefix
#pragma unroll
    for (int i = 0; i < PER; ++i) {
        int idx = base + i;
        if (idx < NN) { cursor[idx] = run; run += c[i]; }
    }
}

__global__ void fill_kernel(const int* __restrict__ src, const int* __restrict__ dst,
                            const float* __restrict__ ew, int* __restrict__ cursor,
                            int2* __restrict__ s_e) {
    int e = blockIdx.x * blockDim.x + threadIdx.x;
    if (e < NE) {
        int d = dst[e];
        int p = atomicAdd(&cursor[d], 1);
        s_e[p] = make_int2(src[e], __float_as_int(ew[e]));
    }
}

// One wave per node (lane owns 8 B of the 512 B row). 8-edge manual unroll:
// 8 independent row gathers in flight per lane -> MLP 8 instead of 1.
__global__ void __launch_bounds__(256)
aggregate_kernel(const uint2* __restrict__ XH64,
                 const int* __restrict__ cursor,
                 const int2* __restrict__ s_e,
                 uint2* __restrict__ AGG64) {
    int wv = threadIdx.x >> 6, lane = threadIdx.x & 63;
    int n = blockIdx.x * 4 + wv;
    int s1 = cursor[n];
    int s0 = (n > 0) ? cursor[n - 1] : 0;
    float a0 = 0.f, a1 = 0.f, a2 = 0.f, a3 = 0.f;
    int i = s0;
    for (; i + 8 <= s1; i += 8) {
        int2 e[8];
#pragma unroll
        for (int j = 0; j < 8; ++j) e[j] = s_e[i + j];
        uint2 u[8];
#pragma unroll
        for (int j = 0; j < 8; ++j) u[j] = XH64[(size_t)e[j].x * 64 + lane];
#pragma unroll
        for (int j = 0; j < 8; ++j) {
            float w = __int_as_float(e[j].y);
            a0 += bf_lo(u[j].x) * w;
            a1 += bf_hi(u[j].x) * w;
            a2 += bf_lo(u[j].y) * w;
            a3 += bf_hi(u[j].y) * w;
        }
    }
    for (; i < s1; ++i) {
        int2 e = s_e[i];
        float w = __int_as_float(e.y);
        uint2 u = XH64[(size_t)e.x * 64 + lane];
        a0 += bf_lo(u.x) * w;
        a1 += bf_hi(u.x) * w;
        a2 += bf_lo(u.y) * w;
        a3 += bf_hi(u.y) * w;
    }
    float inv = (s1 > s0) ? 1.0f / (float)(s1 - s0) : 1.0f;
    uint2 r;
    r.x = pack2bf(a0 * inv, a1 * inv);
    r.y = pack2bf(a2 * inv, a3 * inv);
    AGG64[(size_t)n * 64 + lane] = r;
}

// Fused GEMM + peephole-LSTM.
// Block: 64 rows x 512 cols, 256 threads = 4 waves.
// Wave wv: rows m0 + (wv>>1)*32 .. +32, cols: for each gate g, in-gate cols (wv&1)*64 .. +64.
// All four gates of an output element live in the same lane -> in-register LSTM epilogue.
__global__ void __launch_bounds__(256, 2)
gemm_lstm_kernel(const unsigned short* __restrict__ XH,
                 const unsigned short* __restrict__ AGG,
                 const unsigned short* __restrict__ Wt,
                 const float* __restrict__ bias,
                 const float* __restrict__ wc,
                 const float* __restrict__ C,
                 float* __restrict__ out) {
    __shared__ __align__(16) short Bs[2][16384];  // [buf][col*32 + k], 32 KB each

    int tid = threadIdx.x;
    int wv = tid >> 6, lane = tid & 63;
    int lm = lane & 15, lq = lane >> 4;
    int m0 = blockIdx.x * 64;
    int rg = wv >> 1;   // row group (0/1)
    int h  = wv & 1;    // in-gate column half (0/1)

    floatx4 acc[2][4][4] = {};

    // staging roles: thread t stages col j*64 + (t>>2), 16B piece (t&3)
    const unsigned short* wbase = Wt + (size_t)(tid >> 2) * 512 + (tid & 3) * 8;

    // stage kb=0 into buffer 0
#pragma unroll
    for (int j = 0; j < 8; ++j)
        load_lds16(wbase + (size_t)j * 64 * 512, &Bs[0][j * 2048 + wv * 512]);

    int arow0 = m0 + rg * 32 + lm;        // mt=0 row; mt=1 adds 16
    int afk = lq * 8;

    for (int it = 0; it < 16; ++it) {
        int kb = it * 32;
        __syncthreads();   // drains prior staging (vmcnt0) + guards buffer reuse
        if (it < 15) {
            int kn = kb + 32;
            int buf = (it + 1) & 1;
#pragma unroll
            for (int j = 0; j < 8; ++j)
                load_lds16(wbase + (size_t)j * 64 * 512 + kn, &Bs[buf][j * 2048 + wv * 512]);
        }
        // A frags: U = [aggX | X | aggH | H] segmented over AGG / XH rows of 256 shorts
        const unsigned short* abase = (kb & 128) ? XH : AGG;
        int aoff = (kb & 127) | ((kb & 256) >> 1);
        short8 a0 = *(const short8*)(abase + (size_t)arow0 * 256 + aoff + afk);
        short8 a1 = *(const short8*)(abase + (size_t)(arow0 + 16) * 256 + aoff + afk);

        const short* bsc = Bs[it & 1];
#pragma unroll
        for (int g = 0; g < 4; ++g) {
#pragma unroll
            for (int nt = 0; nt < 4; ++nt) {
                int col = (g << 7) + (h << 6) + (nt << 4) + lm;
                short8 b = *(const short8*)&bsc[(col << 5) + (lq << 3)];
                acc[0][g][nt] = __builtin_amdgcn_mfma_f32_16x16x32_bf16(a0, b, acc[0][g][nt], 0, 0, 0);
                acc[1][g][nt] = __builtin_amdgcn_mfma_f32_16x16x32_bf16(a1, b, acc[1][g][nt], 0, 0, 0);
            }
        }
    }

    // per-lane bias / peephole weights for the 4 in-gate columns this lane owns
    float b_i[4], b_f[4], b_c[4], b_o[4], w0[4], w1[4], w2[4];
#pragma unroll
    for (int nt = 0; nt < 4; ++nt) {
        int cg = (h << 6) + (nt << 4) + lm;
        b_i[nt] = bias[cg];
        b_f[nt] = bias[128 + cg];
        b_c[nt] = bias[256 + cg];
        b_o[nt] = bias[384 + cg];
        w0[nt] = wc[cg];
        w1[nt] = wc[128 + cg];
        w2[nt] = wc[256 + cg];
    }

#pragma unroll
    for (int mt = 0; mt < 2; ++mt) {
#pragma unroll
        for (int r = 0; r < 4; ++r) {
            int row = m0 + rg * 32 + mt * 16 + lq * 4 + r;
            if (row < NN) {
#pragma unroll
                for (int nt = 0; nt < 4; ++nt) {
                    int cg = (h << 6) + (nt << 4) + lm;
                    float c = C[(size_t)row * D + cg];
                    float pi = acc[mt][0][nt][r] + b_i[nt] + w0[nt] * c;
                    float pf = acc[mt][1][nt][r] + b_f[nt] + w1[nt] * c;
                    float pt = acc[mt][2][nt][r] + b_c[nt];
                    float po = acc[mt][3][nt][r] + b_o[nt];
                    float I = sigm(pi);
                    float F = sigm(pf);
                    float T = tanhx(pt);
                    float cn = F * c + I * T;
                    float O = sigm(po + w2[nt] * cn);
                    out[(size_t)row * D + cg] = O * tanhx(cn);
                    out[(size_t)NN * D + (size_t)row * D + cg] = cn;
                }
            }
        }
    }
}

extern "C" void kernel_launch(void* const* d_in, const int* in_sizes, int n_in,
                              void* d_out, int out_size, void* d_ws, size_t ws_size,
                              hipStream_t stream) {
    const float* X  = (const float*)d_in[0];
    const int* ei   = (const int*)d_in[1];
    const float* ew = (const float*)d_in[2];
    const float* H  = (const float*)d_in[3];
    const float* C  = (const float*)d_in[4];
    const float* Wx_l = (const float*)d_in[5];
    const float* Wx_r = (const float*)d_in[6];
    const float* bx   = (const float*)d_in[7];
    const float* Wh_l = (const float*)d_in[8];
    const float* Wh_r = (const float*)d_in[9];
    const float* bh   = (const float*)d_in[10];
    const float* wc   = (const float*)d_in[11];
    const float* bg   = (const float*)d_in[12];
    float* out = (float*)d_out;

    const int* src = ei;
    const int* dst = ei + NE;

    // workspace layout (16B aligned), total ~26.32 MB
    char* ws = (char*)d_ws;
    int*  counts = (int*)(ws + 0);                        //    80,000 B
    int*  cursor = (int*)(ws + 80128);                    //    80,000 B
    int2* s_e    = (int2*)(ws + 160256);                  // 5,120,000 B
    unsigned short* XH  = (unsigned short*)(ws + 5280256);   // NPAD*256*2 = 10,256,384 B
    unsigned short* AGG = (unsigned short*)(ws + 15536640);  // 10,256,384 B
    unsigned short* Wt  = (unsigned short*)(ws + 25793024);  //   524,288 B
    float* bias = (float*)(ws + 26317312);                //     2,048 B

    hipMemsetAsync(counts, 0, NN * sizeof(int), stream);
    prep_kernel<<<NE / 256, 256, 0, stream>>>(dst, counts, (const float4*)X, (const float4*)H,
                                              (unsigned int*)XH, Wx_l, Wx_r, Wh_l, Wh_r,
                                              bx, bh, bg, Wt, bias);
    scan_kernel<<<1, 1024, 0, stream>>>(counts, cursor);
    fill_kernel<<<(NE + 255) / 256, 256, 0, stream>>>(src, dst, ew, cursor, s_e);
    aggregate_kernel<<<NN / 4, 256, 0, stream>>>((const uint2*)XH, cursor, s_e,
                                                 (uint2*)AGG);
    gemm_lstm_kernel<<<(NN + 63) / 64, 256, 0, stream>>>(XH, AGG, Wt, bias, wc, C, out);
}

// Round 4
// 257.435 us; speedup vs baseline: 1.4762x; 1.0023x over previous
//
#include <hip/hip_runtime.h>
#include <math.h>

#define NN 20000
#define NE 640000
#define D  128
#define NPAD 20032   // NN padded by 32 rows for the last GEMM block's A-frag loads
#define NODES_PER_SLICE 2500   // NN / 8 XCDs

typedef __attribute__((ext_vector_type(8))) short short8;
typedef __attribute__((ext_vector_type(4))) float floatx4;

static __device__ __forceinline__ unsigned short f2bf(float f) {
    union { float f; unsigned int u; } v; v.f = f;
    unsigned int u = v.u;
    u += 0x7fff + ((u >> 16) & 1);   // round-to-nearest-even
    return (unsigned short)(u >> 16);
}
static __device__ __forceinline__ unsigned int pack2bf(float a, float b) {
    return (unsigned int)f2bf(a) | ((unsigned int)f2bf(b) << 16);
}
static __device__ __forceinline__ float bf_lo(unsigned int u) {
    union { unsigned int i; float f; } v; v.i = u << 16; return v.f;
}
static __device__ __forceinline__ float bf_hi(unsigned int u) {
    union { unsigned int i; float f; } v; v.i = u & 0xffff0000u; return v.f;
}
static __device__ __forceinline__ float sigm(float x) { return 1.f / (1.f + __expf(-x)); }
static __device__ __forceinline__ float tanhx(float x) { return 1.f - 2.f / (__expf(2.f * x) + 1.f); }

static __device__ __forceinline__ void load_lds16(const void* g, void* l) {
    __builtin_amdgcn_global_load_lds(
        (const __attribute__((address_space(1))) unsigned int*)g,
        (__attribute__((address_space(3))) unsigned int*)l, 16, 0, 0);
}

// Fused independent prep: degree count (atomics), X/H -> bf16 pack, weight
// transpose + bias fuse. NE == NN*32 == 640000 threads exactly.
__global__ void __launch_bounds__(256)
prep_kernel(const int* __restrict__ dst, int* __restrict__ cnt,
            const float4* __restrict__ X4, const float4* __restrict__ H4,
            unsigned int* __restrict__ XH32,
            const float* __restrict__ Wx_l, const float* __restrict__ Wx_r,
            const float* __restrict__ Wh_l, const float* __restrict__ Wh_r,
            const float* __restrict__ bx, const float* __restrict__ bh,
            const float* __restrict__ bg,
            unsigned short* __restrict__ Wt, float* __restrict__ bias) {
    int t = blockIdx.x * 256 + threadIdx.x;  // 0 .. 639999
    // 1) degree histogram
    atomicAdd(&cnt[dst[t]], 1);
    // 2) bf16 pack: XH[n] = [X row (128) | H row (128)]
    float4 x = X4[t];
    float4 h = H4[t];
    int n = t >> 5, q = t & 31;
    unsigned int* row = XH32 + n * 128;
    row[2 * q]          = pack2bf(x.x, x.y);
    row[2 * q + 1]      = pack2bf(x.z, x.w);
    row[64 + 2 * q]     = pack2bf(h.x, h.y);
    row[64 + 2 * q + 1] = pack2bf(h.z, h.w);
    // 3) weight transpose: Wt[col][k], col = gate*128+o
    if (t < 512 * 512) {
        int j = t >> 9;
        int k = t & 511;
        int g = j >> 7;
        int o = j & 127;
        float w;
        if (k < 128)      w = Wx_l[g * 16384 + k * 128 + o];
        else if (k < 256) w = Wx_r[g * 16384 + (k - 128) * 128 + o];
        else if (k < 384) w = Wh_l[g * 16384 + (k - 256) * 128 + o];
        else              w = Wh_r[g * 16384 + (k - 384) * 128 + o];
        Wt[j * 512 + k] = f2bf(w);
        if (k == 0) bias[j] = bx[g * 128 + o] + bh[g * 128 + o] + bg[g * 128 + o];
    }
}

// exclusive prefix of counts -> cursor
__global__ void scan_kernel(const int* __restrict__ cnt, int* __restrict__ cursor) {
    __shared__ int part[1024];
    int t = threadIdx.x;
    const int PER = 20;
    int base = t * PER;
    int c[PER];
    int local = 0;
#pragma unroll
    for (int i = 0; i < PER; ++i) {
        int idx = base + i;
        c[i] = (idx < NN) ? cnt[idx] : 0;
        local += c[i];
    }
    part[t] = local;
    __syncthreads();
    for (int off = 1; off < 1024; off <<= 1) {
        int v = (t >= off) ? part[t - off] : 0;
        __syncthreads();
        part[t] += v;
        __syncthreads();
    }
    int run = part[t] - local;  // exclusive prefix
#pragma unroll
    for (int i = 0; i < PER; ++i) {
        int idx = base + i;
        if (idx < NN) { cursor[idx] = run; run += c[i]; }
    }
}

// XCD-sliced CSR fill. Block handles dst-slice s = blockIdx&7 (heuristic:
// round-robin block->XCD dispatch) over an 8000-edge chunk. A slice's CSR
// positions are a contiguous range of s_p, so each 64B line is dirtied by
// exactly one XCD -> no cross-XCD partial-line write-back amplification.
// Entry packed to 4B: src (15 bits) | bf16(weight) << 16.
__global__ void __launch_bounds__(256)
fill_kernel(const int* __restrict__ src, const int* __restrict__ dst,
            const float* __restrict__ ew, int* __restrict__ cursor,
            unsigned int* __restrict__ s_p) {
    int s = blockIdx.x & 7;
    int chunk = blockIdx.x >> 3;
    int lo = s * NODES_PER_SLICE, hi = lo + NODES_PER_SLICE;
    int e0 = chunk * 8000;
    for (int e = e0 + threadIdx.x; e < e0 + 8000; e += 256) {
        int d = dst[e];
        if (d >= lo && d < hi) {
            int p = atomicAdd(&cursor[d], 1);
            s_p[p] = (unsigned int)src[e] | ((unsigned int)f2bf(ew[e]) << 16);
        }
    }
}

// One wave per node (lane owns 8 B of the 512 B row). 8-edge manual unroll:
// 8 independent row gathers in flight per lane. Block->node mapping matches
// fill's XCD slicing so segment reads hit the local L2.
__global__ void __launch_bounds__(256)
aggregate_kernel(const uint2* __restrict__ XH64,
                 const int* __restrict__ cursor,
                 const unsigned int* __restrict__ s_p,
                 uint2* __restrict__ AGG64) {
    int wv = threadIdx.x >> 6, lane = threadIdx.x & 63;
    int b = blockIdx.x;                 // 0..4999
    int s = b & 7, j = b >> 3;          // j: 0..624
    int n = s * NODES_PER_SLICE + j * 4 + wv;
    int s1 = cursor[n];
    int s0 = (n > 0) ? cursor[n - 1] : 0;
    float a0 = 0.f, a1 = 0.f, a2 = 0.f, a3 = 0.f;
    int i = s0;
    for (; i + 8 <= s1; i += 8) {
        unsigned int e[8];
#pragma unroll
        for (int k = 0; k < 8; ++k) e[k] = s_p[i + k];
        uint2 u[8];
#pragma unroll
        for (int k = 0; k < 8; ++k) u[k] = XH64[(size_t)(e[k] & 0xffff) * 64 + lane];
#pragma unroll
        for (int k = 0; k < 8; ++k) {
            float w = __int_as_float(e[k] & 0xffff0000u);
            a0 += bf_lo(u[k].x) * w;
            a1 += bf_hi(u[k].x) * w;
            a2 += bf_lo(u[k].y) * w;
            a3 += bf_hi(u[k].y) * w;
        }
    }
    for (; i < s1; ++i) {
        unsigned int e = s_p[i];
        float w = __int_as_float(e & 0xffff0000u);
        uint2 u = XH64[(size_t)(e & 0xffff) * 64 + lane];
        a0 += bf_lo(u.x) * w;
        a1 += bf_hi(u.x) * w;
        a2 += bf_lo(u.y) * w;
        a3 += bf_hi(u.y) * w;
    }
    float inv = (s1 > s0) ? 1.0f / (float)(s1 - s0) : 1.0f;
    uint2 r;
    r.x = pack2bf(a0 * inv, a1 * inv);
    r.y = pack2bf(a2 * inv, a3 * inv);
    AGG64[(size_t)n * 64 + lane] = r;
}

// Fused GEMM + peephole-LSTM.
// Block: 64 rows x 512 cols, 256 threads = 4 waves.
// Wave wv: rows m0 + (wv>>1)*32 .. +32, cols: for each gate g, in-gate cols (wv&1)*64 .. +64.
// All four gates of an output element live in the same lane -> in-register LSTM epilogue.
__global__ void __launch_bounds__(256, 2)
gemm_lstm_kernel(const unsigned short* __restrict__ XH,
                 const unsigned short* __restrict__ AGG,
                 const unsigned short* __restrict__ Wt,
                 const float* __restrict__ bias,
                 const float* __restrict__ wc,
                 const float* __restrict__ C,
                 float* __restrict__ out) {
    __shared__ __align__(16) short Bs[2][16384];  // [buf][col*32 + k], 32 KB each

    int tid = threadIdx.x;
    int wv = tid >> 6, lane = tid & 63;
    int lm = lane & 15, lq = lane >> 4;
    int m0 = blockIdx.x * 64;
    int rg = wv >> 1;   // row group (0/1)
    int h  = wv & 1;    // in-gate column half (0/1)

    floatx4 acc[2][4][4] = {};

    // staging roles: thread t stages col j*64 + (t>>2), 16B piece (t&3)
    const unsigned short* wbase = Wt + (size_t)(tid >> 2) * 512 + (tid & 3) * 8;

    // stage kb=0 into buffer 0
#pragma unroll
    for (int j = 0; j < 8; ++j)
        load_lds16(wbase + (size_t)j * 64 * 512, &Bs[0][j * 2048 + wv * 512]);

    int arow0 = m0 + rg * 32 + lm;        // mt=0 row; mt=1 adds 16
    int afk = lq * 8;

    for (int it = 0; it < 16; ++it) {
        int kb = it * 32;
        __syncthreads();   // drains prior staging (vmcnt0) + guards buffer reuse
        if (it < 15) {
            int kn = kb + 32;
            int buf = (it + 1) & 1;
#pragma unroll
            for (int j = 0; j < 8; ++j)
                load_lds16(wbase + (size_t)j * 64 * 512 + kn, &Bs[buf][j * 2048 + wv * 512]);
        }
        // A frags: U = [aggX | X | aggH | H] segmented over AGG / XH rows of 256 shorts
        const unsigned short* abase = (kb & 128) ? XH : AGG;
        int aoff = (kb & 127) | ((kb & 256) >> 1);
        short8 a0 = *(const short8*)(abase + (size_t)arow0 * 256 + aoff + afk);
        short8 a1 = *(const short8*)(abase + (size_t)(arow0 + 16) * 256 + aoff + afk);

        const short* bsc = Bs[it & 1];
#pragma unroll
        for (int g = 0; g < 4; ++g) {
#pragma unroll
            for (int nt = 0; nt < 4; ++nt) {
                int col = (g << 7) + (h << 6) + (nt << 4) + lm;
                short8 b = *(const short8*)&bsc[(col << 5) + (lq << 3)];
                acc[0][g][nt] = __builtin_amdgcn_mfma_f32_16x16x32_bf16(a0, b, acc[0][g][nt], 0, 0, 0);
                acc[1][g][nt] = __builtin_amdgcn_mfma_f32_16x16x32_bf16(a1, b, acc[1][g][nt], 0, 0, 0);
            }
        }
    }

    // per-lane bias / peephole weights for the 4 in-gate columns this lane owns
    float b_i[4], b_f[4], b_c[4], b_o[4], w0[4], w1[4], w2[4];
#pragma unroll
    for (int nt = 0; nt < 4; ++nt) {
        int cg = (h << 6) + (nt << 4) + lm;
        b_i[nt] = bias[cg];
        b_f[nt] = bias[128 + cg];
        b_c[nt] = bias[256 + cg];
        b_o[nt] = bias[384 + cg];
        w0[nt] = wc[cg];
        w1[nt] = wc[128 + cg];
        w2[nt] = wc[256 + cg];
    }

#pragma unroll
    for (int mt = 0; mt < 2; ++mt) {
#pragma unroll
        for (int r = 0; r < 4; ++r) {
            int row = m0 + rg * 32 + mt * 16 + lq * 4 + r;
            if (row < NN) {
#pragma unroll
                for (int nt = 0; nt < 4; ++nt) {
                    int cg = (h << 6) + (nt << 4) + lm;
                    float c = C[(size_t)row * D + cg];
                    float pi = acc[mt][0][nt][r] + b_i[nt] + w0[nt] * c;
                    float pf = acc[mt][1][nt][r] + b_f[nt] + w1[nt] * c;
                    float pt = acc[mt][2][nt][r] + b_c[nt];
                    float po = acc[mt][3][nt][r] + b_o[nt];
                    float I = sigm(pi);
                    float F = sigm(pf);
                    float T = tanhx(pt);
                    float cn = F * c + I * T;
                    float O = sigm(po + w2[nt] * cn);
                    out[(size_t)row * D + cg] = O * tanhx(cn);
                    out[(size_t)NN * D + (size_t)row * D + cg] = cn;
                }
            }
        }
    }
}

extern "C" void kernel_launch(void* const* d_in, const int* in_sizes, int n_in,
                              void* d_out, int out_size, void* d_ws, size_t ws_size,
                              hipStream_t stream) {
    const float* X  = (const float*)d_in[0];
    const int* ei   = (const int*)d_in[1];
    const float* ew = (const float*)d_in[2];
    const float* H  = (const float*)d_in[3];
    const float* C  = (const float*)d_in[4];
    const float* Wx_l = (const float*)d_in[5];
    const float* Wx_r = (const float*)d_in[6];
    const float* bx   = (const float*)d_in[7];
    const float* Wh_l = (const float*)d_in[8];
    const float* Wh_r = (const float*)d_in[9];
    const float* bh   = (const float*)d_in[10];
    const float* wc   = (const float*)d_in[11];
    const float* bg   = (const float*)d_in[12];
    float* out = (float*)d_out;

    const int* src = ei;
    const int* dst = ei + NE;

    // workspace layout (16B aligned), total ~26.32 MB
    char* ws = (char*)d_ws;
    int*  counts = (int*)(ws + 0);                        //    80,000 B
    int*  cursor = (int*)(ws + 80128);                    //    80,000 B
    unsigned int* s_p = (unsigned int*)(ws + 160256);     // 2,560,000 B
    unsigned short* XH  = (unsigned short*)(ws + 5280256);   // NPAD*256*2 = 10,256,384 B
    unsigned short* AGG = (unsigned short*)(ws + 15536640);  // 10,256,384 B
    unsigned short* Wt  = (unsigned short*)(ws + 25793024);  //   524,288 B
    float* bias = (float*)(ws + 26317312);                //     2,048 B

    hipMemsetAsync(counts, 0, NN * sizeof(int), stream);
    prep_kernel<<<NE / 256, 256, 0, stream>>>(dst, counts, (const float4*)X, (const float4*)H,
                                              (unsigned int*)XH, Wx_l, Wx_r, Wh_l, Wh_r,
                                              bx, bh, bg, Wt, bias);
    scan_kernel<<<1, 1024, 0, stream>>>(counts, cursor);
    fill_kernel<<<8 * (NE / 8000), 256, 0, stream>>>(src, dst, ew, cursor, s_p);
    aggregate_kernel<<<NN / 4, 256, 0, stream>>>((const uint2*)XH, cursor, s_p,
                                                 (uint2*)AGG);
    gemm_lstm_kernel<<<(NN + 63) / 64, 256, 0, stream>>>(XH, AGG, Wt, bias, wc, C, out);
}